// Round 6
// baseline (257.687 us; speedup 1.0000x reference)
//
#include <hip/hip_runtime.h>
#include <math.h>

// GCN conv: out = D^{-1/2} (A+I) D^{-1/2} (x W) + b
// d_in[0]=x [100000,128] f32, d_in[1]=edge_index [2,1600000] int32,
// d_in[2]=W1 [128,128] f32, d_in[3]=b1 [128] f32 ; out [100000,128] f32

#define N_NODES 100000
#define N_EDGES 1600000
#define NF 128
#define LDW 136       // padded LDS row stride (bf16 elems)

#define BSHIFT 7                      // 128 nodes per bucket
#define BNODES 128
#define NBUCK 782                     // ceil(100000/128)
#define ECAP 2304                     // bucket capacity (mean 2046 + 5.7 sigma)
#define CHUNK 4096                    // edges per binning block
#define NCHUNK 391                    // ceil(1600000/4096)
#define GEMM_BLOCKS 1563              // ceil(100000/64)

typedef short bf16x8 __attribute__((ext_vector_type(8)));
typedef float f32x4  __attribute__((ext_vector_type(4)));
typedef unsigned short u16;

__device__ inline u16 f2bf(float f) {
    unsigned int u = __float_as_uint(f);
    return (u16)((u + 0x7fffu + ((u >> 16) & 1u)) >> 16);  // RN-even
}

// biased-uint8 unpack: compiles to v_cvt_f32_ubyte0..3 (1 op per value)
__device__ inline f32x4 unpk4u(unsigned int u) {
    f32x4 r;
    r[0] = (float)(u & 0xffu);
    r[1] = (float)((u >> 8) & 0xffu);
    r[2] = (float)((u >> 16) & 0xffu);
    r[3] = (float)(u >> 24);
    return r;
}

// ---------------------------------------------------------------------------
// prep: W [128,128] f32 -> PADDED bf16 W^T image (LDS mirror, 34816 B);
//       block 0 zeroes bcur. 16 blocks.
// ---------------------------------------------------------------------------
__global__ __launch_bounds__(256) void prep_kernel(const float* __restrict__ W,
                                                   u16* __restrict__ Wimg,
                                                   int* __restrict__ bcur) {
    const int t = threadIdx.x;
    if (blockIdx.x == 0)
        for (int b = t; b < NBUCK; b += 256) bcur[b] = 0;
    for (int idx = blockIdx.x * 256 + t; idx < NF * NF; idx += 16 * 256) {
        int n = idx >> 7, k = idx & 127;
        Wimg[n * LDW + k] = f2bf(W[k * NF + n]);
    }
}

// ---------------------------------------------------------------------------
// F1: binning blocks FIRST [0,NCHUNK) (latency hides under gemm blocks).
//     Binning additionally counts per-node degree via global atomics so the
//     fill phase can attach weights to slots. Bucket regions in buf are
//     2*ECAP u32 wide (room for the uint2 {src,w} rewrite by fill3b).
//     GEMM: Wt staged to LDS (padded); A-frags register-direct from x;
//     int8 bounce aliases Wt after a barrier. h8 stored BIASED (+128).
// ---------------------------------------------------------------------------
__global__ __launch_bounds__(256, 4) void fused1_kernel(const float* __restrict__ x,
                                                        const u16* __restrict__ Wimg,
                                                        signed char* __restrict__ h8,
                                                        float* __restrict__ rscale,
                                                        const int* __restrict__ ei,
                                                        int* __restrict__ bcur,
                                                        int* __restrict__ deg,
                                                        unsigned int* __restrict__ buf) {
    __shared__ __align__(16) char smem[39040];
    const int t = threadIdx.x;

    if (blockIdx.x < NCHUNK) {
        // ---------------- binning part (runs first, overlaps gemm) ---------
        unsigned int* ed = (unsigned int*)smem;            // 16384 B
        unsigned int* es = (unsigned int*)(smem + 16384);  // 16384 B
        int* cnt = (int*)(smem + 32768);                   // 3128 B
        int* cur = (int*)(smem + 32768 + 3136);            // 3128 B
        const int c = blockIdx.x;
        for (int b = t; b < NBUCK; b += 256) cnt[b] = 0;
        const int e0 = c * CHUNK;
        #pragma unroll 4
        for (int it = 0; it < CHUNK / 256; ++it) {
            int k = it * 256 + t, e = e0 + k;
            if (e < N_EDGES) {
                ed[k] = (unsigned int)ei[N_EDGES + e];
                es[k] = (unsigned int)ei[e];
            } else ed[k] = 0xFFFFFFFFu;
        }
        __syncthreads();
        #pragma unroll 4
        for (int it = 0; it < CHUNK / 256; ++it) {
            unsigned int d = ed[it * 256 + t];
            if (d != 0xFFFFFFFFu) {
                atomicAdd(&cnt[d >> BSHIFT], 1);
                atomicAdd(&deg[d], 1);           // per-node degree (L2-resident)
            }
        }
        __syncthreads();
        for (int b = t; b < NBUCK; b += 256) {
            int v = cnt[b];
            cur[b] = b * 2 * ECAP + (v ? atomicAdd(&bcur[b], v) : 0);
        }
        __syncthreads();
        #pragma unroll 4
        for (int it = 0; it < CHUNK / 256; ++it) {
            int k = it * 256 + t;
            unsigned int d = ed[k];
            if (d != 0xFFFFFFFFu) {
                int pos = atomicAdd(&cur[d >> BSHIFT], 1);
                buf[pos] = ((d & (BNODES - 1u)) << 17) | es[k];
            }
        }
        return;
    }

    // ---------------- gemm part ----------------
    const int gb = blockIdx.x - NCHUNK;
    const int lane = t & 63;
    const int w = t >> 6;
    const int quad = lane >> 4;
    const int m = lane & 15;
    const int rowbase = gb * 64;
    const int r0 = w * 16;
    const int arow = rowbase + r0 + m;          // this lane's A row
    const bool rv = arow < N_NODES;
    const float4* x4 = (const float4*)x;

    u16* Wt = (u16*)smem;                        // 34816 B padded W^T
    for (int idx = t; idx < (NF * LDW * 2) / 16; idx += 256)
        ((uint4*)Wt)[idx] = ((const uint4*)Wimg)[idx];

    // prefetch all A data (8 float4) before touching LDS results
    float4 xr[8];
    #pragma unroll
    for (int kt = 0; kt < 4; ++kt) {
        if (rv) {
            xr[2 * kt]     = x4[arow * 32 + kt * 8 + quad * 2];
            xr[2 * kt + 1] = x4[arow * 32 + kt * 8 + quad * 2 + 1];
        } else {
            xr[2 * kt] = make_float4(0.f, 0.f, 0.f, 0.f);
            xr[2 * kt + 1] = make_float4(0.f, 0.f, 0.f, 0.f);
        }
    }
    __syncthreads();

    f32x4 acc[8];
    #pragma unroll
    for (int nt = 0; nt < 8; ++nt) acc[nt] = (f32x4){0.f, 0.f, 0.f, 0.f};

    #pragma unroll
    for (int kt = 0; kt < 4; ++kt) {
        bf16x8 a;
        a[0] = (short)f2bf(xr[2 * kt].x);     a[1] = (short)f2bf(xr[2 * kt].y);
        a[2] = (short)f2bf(xr[2 * kt].z);     a[3] = (short)f2bf(xr[2 * kt].w);
        a[4] = (short)f2bf(xr[2 * kt + 1].x); a[5] = (short)f2bf(xr[2 * kt + 1].y);
        a[6] = (short)f2bf(xr[2 * kt + 1].z); a[7] = (short)f2bf(xr[2 * kt + 1].w);
        #pragma unroll
        for (int nt = 0; nt < 8; ++nt) {
            bf16x8 bb = *(const bf16x8*)&Wt[(nt * 16 + m) * LDW + kt * 32 + quad * 8];
            acc[nt] = __builtin_amdgcn_mfma_f32_16x16x32_bf16(a, bb, acc[nt], 0, 0, 0);
        }
    }

    float rmax[4];
    #pragma unroll
    for (int r = 0; r < 4; ++r) {
        float mx = 0.f;
        #pragma unroll
        for (int nt = 0; nt < 8; ++nt) mx = fmaxf(mx, fabsf(acc[nt][r]));
        #pragma unroll
        for (int off = 1; off < 16; off <<= 1) mx = fmaxf(mx, __shfl_xor(mx, off));
        rmax[r] = fmaxf(mx, 1e-20f);
    }

    __syncthreads();     // all Wt reads complete -> safe to alias
    char* xs8 = smem;    // 64 rows x 144B stride = 9216 B bounce
    #pragma unroll
    for (int r = 0; r < 4; ++r) {
        const float inv = 127.f / rmax[r];
        const int row = r0 + quad * 4 + r;
        #pragma unroll
        for (int nt = 0; nt < 8; ++nt) {
            int q = __float2int_rn(acc[nt][r] * inv) + 128;   // biased
            xs8[row * 144 + nt * 16 + m] = (char)q;
        }
        if (m == 0) {
            int grow = rowbase + row;
            if (grow < N_NODES) rscale[grow] = rmax[r] * (1.f / 127.f);
        }
    }
    __syncthreads();

    for (int it = 0; it < 2; ++it) {
        int linear = it * 256 + t;
        int row = linear >> 3, seg = linear & 7;
        int grow = rowbase + row;
        if (grow < N_NODES) {
            uint4 v = *(const uint4*)&xs8[row * 144 + seg * 16];
            ((uint4*)h8)[grow * 8 + seg] = v;
        }
    }
}

// ---------------------------------------------------------------------------
// fill3a: per bucket (782 blocks, 128 thr): scan deg -> nodetab{start(u64
//         units), cnt, dinv, combo} + combo[]. No edge pass.
// ---------------------------------------------------------------------------
__global__ __launch_bounds__(128) void fill3a_kernel(const int* __restrict__ deg,
                                                     const float* __restrict__ rscale,
                                                     float* __restrict__ combo,
                                                     int4* __restrict__ nodetab) {
    __shared__ int lsc[BNODES];
    const int t = threadIdx.x, bkt = blockIdx.x;
    const int n = (bkt << BSHIFT) + t;
    const int c = (n < N_NODES) ? deg[n] : 0;
    lsc[t] = c;
    __syncthreads();
    #pragma unroll
    for (int off = 1; off < BNODES; off <<= 1) {
        int v = lsc[t];
        int add = (t >= off) ? lsc[t - off] : 0;
        __syncthreads();
        lsc[t] = v + add;
        __syncthreads();
    }
    if (n < N_NODES) {
        const int startp = bkt * ECAP + lsc[t] - c;   // uint2 units
        float dv = rsqrtf((float)c + 1.0f);
        float cb = dv * rscale[n];
        combo[n] = cb;
        nodetab[n] = make_int4(startp, c, __float_as_int(dv), __float_as_int(cb));
    }
}

// ---------------------------------------------------------------------------
// fill3b: per bucket: stage u32 run in LDS, gather combo[src] (edge-parallel,
//         deep ILP), scatter uint2{src, w} in place over the bucket region.
// ---------------------------------------------------------------------------
__global__ __launch_bounds__(256) void fill3b_kernel(unsigned int* __restrict__ buf,
                                                     const int* __restrict__ bcur,
                                                     const float* __restrict__ combo,
                                                     const int4* __restrict__ nodetab) {
    __shared__ unsigned int lde[ECAP];
    __shared__ int lcur[BNODES];
    const int t = threadIdx.x, bkt = blockIdx.x;
    if (t < BNODES) {
        int n = (bkt << BSHIFT) + t;
        lcur[t] = (n < N_NODES) ? nodetab[n].x : 0;
    }
    const int cnt = min(bcur[bkt], ECAP);
    const int rbase = bkt * 2 * ECAP;
    for (int e = t; e < cnt; e += 256) lde[e] = buf[rbase + e];
    __syncthreads();
    uint2* sw = (uint2*)buf;
    for (int e = t; e < cnt; e += 256) {
        unsigned int p = lde[e];
        unsigned int src = p & 0x1ffffu;
        float w = combo[src];
        int pos = atomicAdd(&lcur[p >> 17], 1);
        sw[pos] = make_uint2(src, __float_as_uint(w));
    }
}

// ---------------------------------------------------------------------------
// agg: one wave per node. Chain shortened: nodetab -> slotw(uint2 {src,w},
// coalesced) -> shfl -> h8 gather. Biased-ubyte unpack; di and -128*sum(w)
// deferred to epilogue.
// ---------------------------------------------------------------------------
__global__ __launch_bounds__(256) void agg_kernel(const signed char* __restrict__ h8,
                                                  const int4* __restrict__ nodetab,
                                                  const uint2* __restrict__ slotw,
                                                  const float* __restrict__ b,
                                                  float* __restrict__ out) {
    const int wave = threadIdx.x >> 6;
    const int lane = threadIdx.x & 63;
    const int i = blockIdx.x * 4 + wave;
    if (i >= N_NODES) return;

    const int4 ni = nodetab[i];
    const int start = ni.x;
    const int m = ni.y;
    const float di = __int_as_float(ni.z);
    const float ci = __int_as_float(ni.w);
    const int half = lane >> 5;
    const int col = lane & 31;

    const unsigned int* h4 = (const unsigned int*)h8;  // 4 bytes per u32
    f32x4 acc0 = {0.f, 0.f, 0.f, 0.f};
    f32x4 acc1 = {0.f, 0.f, 0.f, 0.f};
    float ws = 0.f;

    for (int base = 0; base < m; base += 64) {
        const int mm = min(m - base, 64);
        uint2 swv = (lane < mm) ? slotw[start + base + lane] : make_uint2(0u, 0u);
        int   s_l  = (int)swv.x;
        float cw_l = __uint_as_float(swv.y);    // 0-weight padding
        const int mu = (mm + 7) & ~7;
        for (int j = 0; j < mu; j += 8) {
            int sj0 = __shfl(s_l, j + 0 + half);
            int sj1 = __shfl(s_l, j + 2 + half);
            int sj2 = __shfl(s_l, j + 4 + half);
            int sj3 = __shfl(s_l, j + 6 + half);
            float wj0 = __shfl(cw_l, j + 0 + half);
            float wj1 = __shfl(cw_l, j + 2 + half);
            float wj2 = __shfl(cw_l, j + 4 + half);
            float wj3 = __shfl(cw_l, j + 6 + half);
            unsigned int u0 = h4[sj0 * 32 + col];
            unsigned int u1 = h4[sj1 * 32 + col];
            unsigned int u2 = h4[sj2 * 32 + col];
            unsigned int u3 = h4[sj3 * 32 + col];
            ws += wj0 + wj1 + wj2 + wj3;
            acc0 += unpk4u(u0) * wj0;
            acc1 += unpk4u(u1) * wj1;
            acc0 += unpk4u(u2) * wj2;
            acc1 += unpk4u(u3) * wj3;
        }
    }

    f32x4 acc = acc0 + acc1;
    #pragma unroll
    for (int c = 0; c < 4; ++c) acc[c] += __shfl_xor(acc[c], 32);
    ws += __shfl_xor(ws, 32);

    if (lane < 32) {
        unsigned int uv = h4[i * 32 + col];
        f32x4 hv = unpk4u(uv);
        float4 bb = ((const float4*)b)[col];
        const float corr = 128.f * (ws + ci);  // bias correction (incl. self)
        float4 o;
        o.x = bb.x + di * (acc[0] + ci * hv[0] - corr);
        o.y = bb.y + di * (acc[1] + ci * hv[1] - corr);
        o.z = bb.z + di * (acc[2] + ci * hv[2] - corr);
        o.w = bb.w + di * (acc[3] + ci * hv[3] - corr);
        ((float4*)out)[i * 32 + col] = o;
    }
}

// ---------------------------------------------------------------------------
extern "C" void kernel_launch(void* const* d_in, const int* in_sizes, int n_in,
                              void* d_out, int out_size, void* d_ws, size_t ws_size,
                              hipStream_t stream) {
    const float* x  = (const float*)d_in[0];
    const int*   ei = (const int*)d_in[1];
    const float* W  = (const float*)d_in[2];
    const float* b  = (const float*)d_in[3];
    float* out = (float*)d_out;

    // ws layout (4B-unit offsets):
    // h8 [0..3.2M) | rscale 3.3M | combo 3.45M | nodetab 3.6M..4.0M |
    // deg 4.02M | bcur 4.13M | Wimg 4.14M (34.8KB) |
    // buf [4.15M .. 4.15M + 782*2*2304 = 7.754M)   (~31 MB total)
    signed char* h8 = (signed char*)d_ws;
    float* rscale = (float*)d_ws + 3300000;
    float* combo  = (float*)d_ws + 3450000;
    int4*  nodetab = (int4*)((int*)d_ws + 3600000);
    int*   deg    = (int*)d_ws + 4020000;
    int*   bcur   = (int*)d_ws + 4130000;
    u16*   Wimg   = (u16*)((int*)d_ws + 4140000);
    unsigned int* buf = (unsigned int*)d_ws + 4150000;

    hipMemsetAsync(deg, 0, N_NODES * sizeof(int), stream);
    prep_kernel<<<16, 256, 0, stream>>>(W, Wimg, bcur);
    fused1_kernel<<<NCHUNK + GEMM_BLOCKS, 256, 0, stream>>>(x, Wimg, h8, rscale,
                                                            ei, bcur, deg, buf);
    fill3a_kernel<<<NBUCK, 128, 0, stream>>>(deg, rscale, combo, nodetab);
    fill3b_kernel<<<NBUCK, 256, 0, stream>>>(buf, bcur, combo, nodetab);
    agg_kernel<<<(N_NODES + 3) / 4, 256, 0, stream>>>(h8, nodetab,
                                                      (const uint2*)buf, b, out);
}

// Round 7
// 191.073 us; speedup vs baseline: 1.3486x; 1.3486x over previous
//
#include <hip/hip_runtime.h>
#include <math.h>

// GCN conv: out = D^{-1/2} (A+I) D^{-1/2} (x W) + b
// d_in[0]=x [100000,128] f32, d_in[1]=edge_index [2,1600000] int32,
// d_in[2]=W1 [128,128] f32, d_in[3]=b1 [128] f32 ; out [100000,128] f32

#define N_NODES 100000
#define N_EDGES 1600000
#define NF 128
#define LDW 136       // padded LDS row stride (bf16 elems)

#define BSHIFT 7                      // 128 nodes per bucket
#define BNODES 128
#define NBUCK 782                     // ceil(100000/128)
#define ECAP 2432                     // bucket capacity (mean 2046 + 8.6 sigma)
#define HCAP 1536                     // half-bucket slot capacity (mean 1023)
#define CHUNK 4096                    // edges per binning block
#define NCHUNK 391                    // ceil(1600000/4096)
#define GEMM_BLOCKS 1563              // ceil(100000/64)

typedef short bf16x8 __attribute__((ext_vector_type(8)));
typedef float f32x4  __attribute__((ext_vector_type(4)));
typedef unsigned short u16;

__device__ inline u16 f2bf(float f) {
    unsigned int u = __float_as_uint(f);
    return (u16)((u + 0x7fffu + ((u >> 16) & 1u)) >> 16);  // RN-even
}

// biased-uint8 unpack: compiles to v_cvt_f32_ubyte0..3 (1 op per value)
__device__ inline f32x4 unpk4u(unsigned int u) {
    f32x4 r;
    r[0] = (float)(u & 0xffu);
    r[1] = (float)((u >> 8) & 0xffu);
    r[2] = (float)((u >> 16) & 0xffu);
    r[3] = (float)(u >> 24);
    return r;
}

// ---------------------------------------------------------------------------
// prep: W [128,128] f32 -> PADDED bf16 W^T image (LDS mirror, 34816 B);
//       block 0 zeroes bcur. 16 blocks.   (identical to round-5)
// ---------------------------------------------------------------------------
__global__ __launch_bounds__(256) void prep_kernel(const float* __restrict__ W,
                                                   u16* __restrict__ Wimg,
                                                   int* __restrict__ bcur) {
    const int t = threadIdx.x;
    if (blockIdx.x == 0)
        for (int b = t; b < NBUCK; b += 256) bcur[b] = 0;
    for (int idx = blockIdx.x * 256 + t; idx < NF * NF; idx += 16 * 256) {
        int n = idx >> 7, k = idx & 127;
        Wimg[n * LDW + k] = f2bf(W[k * NF + n]);
    }
}

// ---------------------------------------------------------------------------
// F1: binning blocks FIRST [0,NCHUNK) (latency hides under gemm blocks).
//     GEMM: Wt staged to LDS (padded); A-frags register-direct from x;
//     int8 bounce aliases Wt after a barrier. h8 stored BIASED (+128).
//     (identical to round-5)
// ---------------------------------------------------------------------------
__global__ __launch_bounds__(256, 4) void fused1_kernel(const float* __restrict__ x,
                                                        const u16* __restrict__ Wimg,
                                                        signed char* __restrict__ h8,
                                                        float* __restrict__ rscale,
                                                        const int* __restrict__ ei,
                                                        int* __restrict__ bcur,
                                                        unsigned int* __restrict__ ebuf) {
    __shared__ __align__(16) char smem[39040];
    const int t = threadIdx.x;

    if (blockIdx.x < NCHUNK) {
        // ---------------- binning part (runs first, overlaps gemm) ---------
        unsigned int* ed = (unsigned int*)smem;            // 16384 B
        unsigned int* es = (unsigned int*)(smem + 16384);  // 16384 B
        int* cnt = (int*)(smem + 32768);                   // 3128 B
        int* cur = (int*)(smem + 32768 + 3136);            // 3128 B
        const int c = blockIdx.x;
        for (int b = t; b < NBUCK; b += 256) cnt[b] = 0;
        const int e0 = c * CHUNK;
        #pragma unroll 4
        for (int it = 0; it < CHUNK / 256; ++it) {
            int k = it * 256 + t, e = e0 + k;
            if (e < N_EDGES) {
                ed[k] = (unsigned int)ei[N_EDGES + e];
                es[k] = (unsigned int)ei[e];
            } else ed[k] = 0xFFFFFFFFu;
        }
        __syncthreads();
        #pragma unroll 4
        for (int it = 0; it < CHUNK / 256; ++it) {
            unsigned int d = ed[it * 256 + t];
            if (d != 0xFFFFFFFFu) atomicAdd(&cnt[d >> BSHIFT], 1);
        }
        __syncthreads();
        for (int b = t; b < NBUCK; b += 256) {
            int v = cnt[b];
            cur[b] = b * ECAP + (v ? atomicAdd(&bcur[b], v) : 0);
        }
        __syncthreads();
        #pragma unroll 4
        for (int it = 0; it < CHUNK / 256; ++it) {
            int k = it * 256 + t;
            unsigned int d = ed[k];
            if (d != 0xFFFFFFFFu) {
                int pos = atomicAdd(&cur[d >> BSHIFT], 1);
                ebuf[pos] = ((d & (BNODES - 1u)) << 17) | es[k];
            }
        }
        return;
    }

    // ---------------- gemm part ----------------
    const int gb = blockIdx.x - NCHUNK;
    const int lane = t & 63;
    const int w = t >> 6;
    const int quad = lane >> 4;
    const int m = lane & 15;
    const int rowbase = gb * 64;
    const int r0 = w * 16;
    const int arow = rowbase + r0 + m;          // this lane's A row
    const bool rv = arow < N_NODES;
    const float4* x4 = (const float4*)x;

    u16* Wt = (u16*)smem;                        // 34816 B padded W^T
    for (int idx = t; idx < (NF * LDW * 2) / 16; idx += 256)
        ((uint4*)Wt)[idx] = ((const uint4*)Wimg)[idx];

    // prefetch all A data (8 float4) before touching LDS results
    float4 xr[8];
    #pragma unroll
    for (int kt = 0; kt < 4; ++kt) {
        if (rv) {
            xr[2 * kt]     = x4[arow * 32 + kt * 8 + quad * 2];
            xr[2 * kt + 1] = x4[arow * 32 + kt * 8 + quad * 2 + 1];
        } else {
            xr[2 * kt] = make_float4(0.f, 0.f, 0.f, 0.f);
            xr[2 * kt + 1] = make_float4(0.f, 0.f, 0.f, 0.f);
        }
    }
    __syncthreads();

    f32x4 acc[8];
    #pragma unroll
    for (int nt = 0; nt < 8; ++nt) acc[nt] = (f32x4){0.f, 0.f, 0.f, 0.f};

    #pragma unroll
    for (int kt = 0; kt < 4; ++kt) {
        bf16x8 a;
        a[0] = (short)f2bf(xr[2 * kt].x);     a[1] = (short)f2bf(xr[2 * kt].y);
        a[2] = (short)f2bf(xr[2 * kt].z);     a[3] = (short)f2bf(xr[2 * kt].w);
        a[4] = (short)f2bf(xr[2 * kt + 1].x); a[5] = (short)f2bf(xr[2 * kt + 1].y);
        a[6] = (short)f2bf(xr[2 * kt + 1].z); a[7] = (short)f2bf(xr[2 * kt + 1].w);
        #pragma unroll
        for (int nt = 0; nt < 8; ++nt) {
            bf16x8 bb = *(const bf16x8*)&Wt[(nt * 16 + m) * LDW + kt * 32 + quad * 8];
            acc[nt] = __builtin_amdgcn_mfma_f32_16x16x32_bf16(a, bb, acc[nt], 0, 0, 0);
        }
    }

    float rmax[4];
    #pragma unroll
    for (int r = 0; r < 4; ++r) {
        float mx = 0.f;
        #pragma unroll
        for (int nt = 0; nt < 8; ++nt) mx = fmaxf(mx, fabsf(acc[nt][r]));
        #pragma unroll
        for (int off = 1; off < 16; off <<= 1) mx = fmaxf(mx, __shfl_xor(mx, off));
        rmax[r] = fmaxf(mx, 1e-20f);
    }

    __syncthreads();     // all Wt reads complete -> safe to alias
    char* xs8 = smem;    // 64 rows x 144B stride = 9216 B bounce
    #pragma unroll
    for (int r = 0; r < 4; ++r) {
        const float inv = 127.f / rmax[r];
        const int row = r0 + quad * 4 + r;
        #pragma unroll
        for (int nt = 0; nt < 8; ++nt) {
            int q = __float2int_rn(acc[nt][r] * inv) + 128;   // biased
            xs8[row * 144 + nt * 16 + m] = (char)q;
        }
        if (m == 0) {
            int grow = rowbase + row;
            if (grow < N_NODES) rscale[grow] = rmax[r] * (1.f / 127.f);
        }
    }
    __syncthreads();

    for (int it = 0; it < 2; ++it) {
        int linear = it * 256 + t;
        int row = linear >> 3, seg = linear & 7;
        int grow = rowbase + row;
        if (grow < N_NODES) {
            uint4 v = *(const uint4*)&xs8[row * 144 + seg * 16];
            ((uint4*)h8)[grow * 8 + seg] = v;
        }
    }
}

// ---------------------------------------------------------------------------
// comboK: per bucket, count per-node degree from the bucket run (LDS
//         atomics), write combo = rsqrt(deg+1)*rscale. Light (782 blocks).
// ---------------------------------------------------------------------------
__global__ __launch_bounds__(256) void comboK_kernel(const unsigned int* __restrict__ ebuf,
                                                     const int* __restrict__ bcur,
                                                     const float* __restrict__ rscale,
                                                     float* __restrict__ combo) {
    __shared__ int lcnt[BNODES];
    const int t = threadIdx.x, bkt = blockIdx.x;
    if (t < BNODES) lcnt[t] = 0;
    __syncthreads();
    const int cnt = min(bcur[bkt], ECAP);
    for (int e = t; e < cnt; e += 256)
        atomicAdd(&lcnt[ebuf[bkt * ECAP + e] >> 17], 1);
    __syncthreads();
    if (t < BNODES) {
        int n = (bkt << BSHIFT) + t;
        if (n < N_NODES)
            combo[n] = rsqrtf((float)lcnt[t] + 1.0f) * rscale[n];
    }
}

// ---------------------------------------------------------------------------
// aggB: one block per HALF bucket (64 nodes, 1564 blocks). Stage/filter the
// bucket run, LDS-scatter own nodes' srcs into lslot (the old fill3 scatter,
// but never touching HBM), then 4 waves x 16 nodes run the proven round-5
// gather loop with slots from LDS. No nodetab, no global slot array.
// ---------------------------------------------------------------------------
__global__ __launch_bounds__(256) void aggB_kernel(const unsigned int* __restrict__ ebuf,
                                                   const int* __restrict__ bcur,
                                                   const float* __restrict__ rscale,
                                                   const float* __restrict__ combo,
                                                   const signed char* __restrict__ h8,
                                                   const float* __restrict__ b,
                                                   float* __restrict__ out) {
    __shared__ unsigned int lslot[HCAP];
    __shared__ int lcnt[64];
    __shared__ int lbase[64];
    __shared__ int lcur[64];
    const int t = threadIdx.x;
    const int bkt = blockIdx.x >> 1;
    const int hb  = blockIdx.x & 1;
    const int n0  = (bkt << BSHIFT) + hb * 64;   // first node of this half
    const unsigned lo = (unsigned)(hb * 64), hi = lo + 64u;
    const int cnt = min(bcur[bkt], ECAP);
    const int rbase = bkt * ECAP;

    if (t < 64) lcnt[t] = 0;
    __syncthreads();
    for (int e = t; e < cnt; e += 256) {
        unsigned p = ebuf[rbase + e];
        unsigned ld = p >> 17;
        if (ld >= lo && ld < hi) atomicAdd(&lcnt[ld - lo], 1);
    }
    __syncthreads();
    if (t < 64) {                      // wave-0 shfl scan of 64 counts
        int v = lcnt[t];
        int s = v;
        #pragma unroll
        for (int off = 1; off < 64; off <<= 1) {
            int u = __shfl_up(s, off);
            if (t >= off) s += u;
        }
        lbase[t] = s - v;
        lcur[t]  = s - v;
    }
    __syncthreads();
    for (int e = t; e < cnt; e += 256) {
        unsigned p = ebuf[rbase + e];
        unsigned ld = p >> 17;
        if (ld >= lo && ld < hi) {
            int pos = atomicAdd(&lcur[ld - lo], 1);
            if (pos < HCAP) lslot[pos] = p & 0x1ffffu;
        }
    }
    __syncthreads();

    // ---------------- aggregation: 4 waves x 16 nodes ----------------
    const int wave = t >> 6;
    const int lane = t & 63;
    const int half = lane >> 5;
    const int col  = lane & 31;
    const unsigned int* h4 = (const unsigned int*)h8;
    float4 bb = make_float4(0.f, 0.f, 0.f, 0.f);
    if (lane < 32) bb = ((const float4*)b)[col];

    for (int nn = 0; nn < 16; ++nn) {
        const int li = wave * 16 + nn;
        const int i  = n0 + li;
        if (i >= N_NODES) continue;            // uniform per wave
        const int start = lbase[li];
        const int m     = lcnt[li];
        const float di  = rsqrtf((float)m + 1.0f);
        const float ci  = di * rscale[i];

        f32x4 acc0 = {0.f, 0.f, 0.f, 0.f};
        f32x4 acc1 = {0.f, 0.f, 0.f, 0.f};
        float ws = 0.f;

        for (int base = 0; base < m; base += 64) {
            const int mm = min(m - base, 64);
            int   s_l  = (lane < mm) ? (int)lslot[start + base + lane] : 0;
            float cw_l = (lane < mm) ? combo[s_l] : 0.0f;   // 0-weight padding
            const int mu = (mm + 7) & ~7;
            for (int j = 0; j < mu; j += 8) {
                int sj0 = __shfl(s_l, j + 0 + half);
                int sj1 = __shfl(s_l, j + 2 + half);
                int sj2 = __shfl(s_l, j + 4 + half);
                int sj3 = __shfl(s_l, j + 6 + half);
                float wj0 = __shfl(cw_l, j + 0 + half);
                float wj1 = __shfl(cw_l, j + 2 + half);
                float wj2 = __shfl(cw_l, j + 4 + half);
                float wj3 = __shfl(cw_l, j + 6 + half);
                unsigned int u0 = h4[sj0 * 32 + col];
                unsigned int u1 = h4[sj1 * 32 + col];
                unsigned int u2 = h4[sj2 * 32 + col];
                unsigned int u3 = h4[sj3 * 32 + col];
                ws += wj0 + wj1 + wj2 + wj3;
                acc0 += unpk4u(u0) * wj0;
                acc1 += unpk4u(u1) * wj1;
                acc0 += unpk4u(u2) * wj2;
                acc1 += unpk4u(u3) * wj3;
            }
        }

        f32x4 acc = acc0 + acc1;
        #pragma unroll
        for (int c = 0; c < 4; ++c) acc[c] += __shfl_xor(acc[c], 32);
        ws += __shfl_xor(ws, 32);

        if (lane < 32) {
            unsigned int uv = h4[i * 32 + col];
            f32x4 hv = unpk4u(uv);
            const float corr = 128.f * (ws + ci);  // bias corr (incl. self)
            float4 o;
            o.x = bb.x + di * (acc[0] + ci * hv[0] - corr);
            o.y = bb.y + di * (acc[1] + ci * hv[1] - corr);
            o.z = bb.z + di * (acc[2] + ci * hv[2] - corr);
            o.w = bb.w + di * (acc[3] + ci * hv[3] - corr);
            ((float4*)out)[i * 32 + col] = o;
        }
    }
}

// ---------------------------------------------------------------------------
extern "C" void kernel_launch(void* const* d_in, const int* in_sizes, int n_in,
                              void* d_out, int out_size, void* d_ws, size_t ws_size,
                              hipStream_t stream) {
    const float* x  = (const float*)d_in[0];
    const int*   ei = (const int*)d_in[1];
    const float* W  = (const float*)d_in[2];
    const float* b  = (const float*)d_in[3];
    float* out = (float*)d_out;

    // ws layout (4B-unit offsets):
    // h8 [0..3.2M) | rscale 3.3M | combo 3.45M | bcur 4.13M |
    // Wimg 4.14M (34.8KB) | ebuf [4.3M .. 4.3M+782*2432=6.20M)
    signed char* h8 = (signed char*)d_ws;
    float* rscale = (float*)d_ws + 3300000;
    float* combo  = (float*)d_ws + 3450000;
    int*   bcur   = (int*)d_ws + 4130000;
    u16*   Wimg   = (u16*)((int*)d_ws + 4140000);
    unsigned int* ebuf = (unsigned int*)d_ws + 4300000;

    prep_kernel<<<16, 256, 0, stream>>>(W, Wimg, bcur);
    fused1_kernel<<<NCHUNK + GEMM_BLOCKS, 256, 0, stream>>>(x, Wimg, h8, rscale,
                                                            ei, bcur, ebuf);
    comboK_kernel<<<NBUCK, 256, 0, stream>>>(ebuf, bcur, rscale, combo);
    aggB_kernel<<<NBUCK * 2, 256, 0, stream>>>(ebuf, bcur, rscale, combo, h8, b, out);
}

// Round 9
// 184.915 us; speedup vs baseline: 1.3935x; 1.0333x over previous
//
#include <hip/hip_runtime.h>
#include <math.h>

// GCN conv: out = D^{-1/2} (A+I) D^{-1/2} (x W) + b
// d_in[0]=x [100000,128] f32, d_in[1]=edge_index [2,1600000] int32,
// d_in[2]=W1 [128,128] f32, d_in[3]=b1 [128] f32 ; out [100000,128] f32

#define N_NODES 100000
#define N_EDGES 1600000
#define NF 128
#define LDW 136       // padded LDS row stride (bf16 elems)

#define BSHIFT 7                      // 128 nodes per bucket
#define BNODES 128
#define NBUCK 782                     // ceil(100000/128)
#define ECAP 2432                     // bucket cap (mean 2046 + 8.6 sigma)
#define HCAP 1536                     // half-bucket slot capacity (mean 1023)
#define CHUNK 4096                    // edges per binning block
#define NCHUNK 391                    // ceil(1600000/4096)
#define GEMM_BLOCKS 1563              // ceil(100000/64)

typedef short bf16x8 __attribute__((ext_vector_type(8)));
typedef float f32x4  __attribute__((ext_vector_type(4)));
typedef unsigned short u16;

__device__ inline u16 f2bf(float f) {
    unsigned int u = __float_as_uint(f);
    return (u16)((u + 0x7fffu + ((u >> 16) & 1u)) >> 16);  // RN-even
}

// biased-uint8 unpack: compiles to v_cvt_f32_ubyte0..3 (1 op per value)
__device__ inline f32x4 unpk4u(unsigned int u) {
    f32x4 r;
    r[0] = (float)(u & 0xffu);
    r[1] = (float)((u >> 8) & 0xffu);
    r[2] = (float)((u >> 16) & 0xffu);
    r[3] = (float)(u >> 24);
    return r;
}

// ---------------------------------------------------------------------------
// prep: W [128,128] f32 -> PADDED bf16 W^T image (LDS mirror, 34816 B);
//       block 0 zeroes bcur. 16 blocks.   (round-7 proven)
// ---------------------------------------------------------------------------
__global__ __launch_bounds__(256) void prep_kernel(const float* __restrict__ W,
                                                   u16* __restrict__ Wimg,
                                                   int* __restrict__ bcur) {
    const int t = threadIdx.x;
    if (blockIdx.x == 0)
        for (int b = t; b < NBUCK; b += 256) bcur[b] = 0;
    for (int idx = blockIdx.x * 256 + t; idx < NF * NF; idx += 16 * 256) {
        int n = idx >> 7, k = idx & 127;
        Wimg[n * LDW + k] = f2bf(W[k * NF + n]);
    }
}

// ---------------------------------------------------------------------------
// F1: binning blocks FIRST [0,NCHUNK); GEMM blocks after.  (round-7 proven)
// ---------------------------------------------------------------------------
__global__ __launch_bounds__(256, 4) void fused1_kernel(const float* __restrict__ x,
                                                        const u16* __restrict__ Wimg,
                                                        signed char* __restrict__ h8,
                                                        float* __restrict__ rscale,
                                                        const int* __restrict__ ei,
                                                        int* __restrict__ bcur,
                                                        unsigned int* __restrict__ ebuf) {
    __shared__ __align__(16) char smem[39040];
    const int t = threadIdx.x;

    if (blockIdx.x < NCHUNK) {
        // ---------------- binning part (runs first, overlaps gemm) ---------
        unsigned int* ed = (unsigned int*)smem;            // 16384 B
        unsigned int* es = (unsigned int*)(smem + 16384);  // 16384 B
        int* cnt = (int*)(smem + 32768);                   // 3128 B
        int* cur = (int*)(smem + 32768 + 3136);            // 3128 B
        const int c = blockIdx.x;
        for (int b = t; b < NBUCK; b += 256) cnt[b] = 0;
        const int e0 = c * CHUNK;
        #pragma unroll 4
        for (int it = 0; it < CHUNK / 256; ++it) {
            int k = it * 256 + t, e = e0 + k;
            if (e < N_EDGES) {
                ed[k] = (unsigned int)ei[N_EDGES + e];
                es[k] = (unsigned int)ei[e];
            } else ed[k] = 0xFFFFFFFFu;
        }
        __syncthreads();
        #pragma unroll 4
        for (int it = 0; it < CHUNK / 256; ++it) {
            unsigned int d = ed[it * 256 + t];
            if (d != 0xFFFFFFFFu) atomicAdd(&cnt[d >> BSHIFT], 1);
        }
        __syncthreads();
        for (int b = t; b < NBUCK; b += 256) {
            int v = cnt[b];
            cur[b] = b * ECAP + (v ? atomicAdd(&bcur[b], v) : 0);
        }
        __syncthreads();
        #pragma unroll 4
        for (int it = 0; it < CHUNK / 256; ++it) {
            int k = it * 256 + t;
            unsigned int d = ed[k];
            if (d != 0xFFFFFFFFu) {
                int pos = atomicAdd(&cur[d >> BSHIFT], 1);
                ebuf[pos] = ((d & (BNODES - 1u)) << 17) | es[k];
            }
        }
        return;
    }

    // ---------------- gemm part (round-5 proven) ----------------
    const int gb = blockIdx.x - NCHUNK;
    const int lane = t & 63;
    const int w = t >> 6;
    const int quad = lane >> 4;
    const int m = lane & 15;
    const int rowbase = gb * 64;
    const int r0 = w * 16;
    const int arow = rowbase + r0 + m;          // this lane's A row
    const bool rv = arow < N_NODES;
    const float4* x4 = (const float4*)x;

    u16* Wt = (u16*)smem;                        // 34816 B padded W^T
    for (int idx = t; idx < (NF * LDW * 2) / 16; idx += 256)
        ((uint4*)Wt)[idx] = ((const uint4*)Wimg)[idx];

    // prefetch all A data (8 float4) before touching LDS results
    float4 xr[8];
    #pragma unroll
    for (int kt = 0; kt < 4; ++kt) {
        if (rv) {
            xr[2 * kt]     = x4[arow * 32 + kt * 8 + quad * 2];
            xr[2 * kt + 1] = x4[arow * 32 + kt * 8 + quad * 2 + 1];
        } else {
            xr[2 * kt] = make_float4(0.f, 0.f, 0.f, 0.f);
            xr[2 * kt + 1] = make_float4(0.f, 0.f, 0.f, 0.f);
        }
    }
    __syncthreads();

    f32x4 acc[8];
    #pragma unroll
    for (int nt = 0; nt < 8; ++nt) acc[nt] = (f32x4){0.f, 0.f, 0.f, 0.f};

    #pragma unroll
    for (int kt = 0; kt < 4; ++kt) {
        bf16x8 a;
        a[0] = (short)f2bf(xr[2 * kt].x);     a[1] = (short)f2bf(xr[2 * kt].y);
        a[2] = (short)f2bf(xr[2 * kt].z);     a[3] = (short)f2bf(xr[2 * kt].w);
        a[4] = (short)f2bf(xr[2 * kt + 1].x); a[5] = (short)f2bf(xr[2 * kt + 1].y);
        a[6] = (short)f2bf(xr[2 * kt + 1].z); a[7] = (short)f2bf(xr[2 * kt + 1].w);
        #pragma unroll
        for (int nt = 0; nt < 8; ++nt) {
            bf16x8 bb = *(const bf16x8*)&Wt[(nt * 16 + m) * LDW + kt * 32 + quad * 8];
            acc[nt] = __builtin_amdgcn_mfma_f32_16x16x32_bf16(a, bb, acc[nt], 0, 0, 0);
        }
    }

    float rmax[4];
    #pragma unroll
    for (int r = 0; r < 4; ++r) {
        float mx = 0.f;
        #pragma unroll
        for (int nt = 0; nt < 8; ++nt) mx = fmaxf(mx, fabsf(acc[nt][r]));
        #pragma unroll
        for (int off = 1; off < 16; off <<= 1) mx = fmaxf(mx, __shfl_xor(mx, off));
        rmax[r] = fmaxf(mx, 1e-20f);
    }

    __syncthreads();     // all Wt reads complete -> safe to alias
    char* xs8 = smem;    // 64 rows x 144B stride = 9216 B bounce
    #pragma unroll
    for (int r = 0; r < 4; ++r) {
        const float inv = 127.f / rmax[r];
        const int row = r0 + quad * 4 + r;
        #pragma unroll
        for (int nt = 0; nt < 8; ++nt) {
            int q = __float2int_rn(acc[nt][r] * inv) + 128;   // biased
            xs8[row * 144 + nt * 16 + m] = (char)q;
        }
        if (m == 0) {
            int grow = rowbase + row;
            if (grow < N_NODES) rscale[grow] = rmax[r] * (1.f / 127.f);
        }
    }
    __syncthreads();

    for (int it = 0; it < 2; ++it) {
        int linear = it * 256 + t;
        int row = linear >> 3, seg = linear & 7;
        int grow = rowbase + row;
        if (grow < N_NODES) {
            uint4 v = *(const uint4*)&xs8[row * 144 + seg * 16];
            ((uint4*)h8)[grow * 8 + seg] = v;
        }
    }
}

// ---------------------------------------------------------------------------
// comboK: per bucket, count per-node degree from the bucket run (LDS
//         atomics), write combo = rsqrt(deg+1)*rscale.   (round-7 proven)
// ---------------------------------------------------------------------------
__global__ __launch_bounds__(256) void comboK_kernel(const unsigned int* __restrict__ ebuf,
                                                     const int* __restrict__ bcur,
                                                     const float* __restrict__ rscale,
                                                     float* __restrict__ combo) {
    __shared__ int lcnt[BNODES];
    const int t = threadIdx.x, bkt = blockIdx.x;
    if (t < BNODES) lcnt[t] = 0;
    __syncthreads();
    const int cnt = min(bcur[bkt], ECAP);
    for (int e = t; e < cnt; e += 256)
        atomicAdd(&lcnt[ebuf[bkt * ECAP + e] >> 17], 1);
    __syncthreads();
    if (t < BNODES) {
        int n = (bkt << BSHIFT) + t;
        if (n < N_NODES)
            combo[n] = rsqrtf((float)lcnt[t] + 1.0f) * rscale[n];
    }
}

// ---------------------------------------------------------------------------
// aggB: one block per HALF bucket (64 nodes, 1564 blocks). R7-proven
// count -> scan -> scatter skeleton; NEW: (1) weights fetched edge-parallel
// during scatter and stored as lsw={src,w} pairs; (2) gather runs 2 nodes
// per wave (one per 32-lane half) with slots/weights via uniform-address
// LDS reads (broadcast b64) -> no per-edge shfl, no cross-lane reduce.
// Tail edges predicated (weight->0, src->0); lsw has +4 pad so reads are
// always in-bounds; predication means uninit LDS is never consumed.
// ---------------------------------------------------------------------------
__global__ __launch_bounds__(256) void aggB_kernel(const unsigned int* __restrict__ ebuf,
                                                   const int* __restrict__ bcur,
                                                   const float* __restrict__ rscale,
                                                   const float* __restrict__ combo,
                                                   const signed char* __restrict__ h8,
                                                   const float* __restrict__ b,
                                                   float* __restrict__ out) {
    __shared__ __align__(8) uint2 lsw[HCAP + 4];
    __shared__ int lcnt[64];
    __shared__ int lbase[64];
    __shared__ int lcur[64];
    const int t = threadIdx.x;
    const int bkt = blockIdx.x >> 1;
    const int hb  = blockIdx.x & 1;
    const int n0  = (bkt << BSHIFT) + hb * 64;   // first node of this half
    const unsigned lo = (unsigned)(hb * 64), hi = lo + 64u;
    const int cnt = min(bcur[bkt], ECAP);
    const int rbase = bkt * ECAP;

    if (t < 64) lcnt[t] = 0;
    __syncthreads();
    for (int e = t; e < cnt; e += 256) {
        unsigned p = ebuf[rbase + e];
        unsigned ld = p >> 17;
        if (ld >= lo && ld < hi) atomicAdd(&lcnt[ld - lo], 1);
    }
    __syncthreads();
    if (t < 64) {                      // wave-0 shfl scan of 64 counts
        int v = lcnt[t];
        int s = v;
        #pragma unroll
        for (int off = 1; off < 64; off <<= 1) {
            int u = __shfl_up(s, off);
            if (t >= off) s += u;
        }
        lbase[t] = s - v;
        lcur[t]  = s - v;
    }
    __syncthreads();
    for (int e = t; e < cnt; e += 256) {
        unsigned p = ebuf[rbase + e];
        unsigned ld = p >> 17;
        if (ld >= lo && ld < hi) {
            unsigned src = p & 0x1ffffu;
            float wv = combo[src];               // edge-parallel gather
            int pos = atomicAdd(&lcur[ld - lo], 1);
            if (pos < HCAP) lsw[pos] = make_uint2(src, __float_as_uint(wv));
        }
    }
    __syncthreads();

    // ---------------- gather: 4 waves x 8 node-pairs ----------------
    const int wave = t >> 6;
    const int lane = t & 63;
    const int half = lane >> 5;
    const int col  = lane & 31;
    const unsigned int* h4 = (const unsigned int*)h8;
    const float4 bb = ((const float4*)b)[col];

    for (int pp = 0; pp < 8; ++pp) {
        const int li = wave * 16 + pp * 2 + half;   // this half's node
        const int i  = n0 + li;
        const bool valid = i < N_NODES;
        const int deg  = valid ? lcnt[li] : 0;
        const int base = valid ? lbase[li] : 0;
        const int m    = min(deg, HCAP - base);     // defensive clamp

        f32x4 a0 = {0.f,0.f,0.f,0.f}, a1 = {0.f,0.f,0.f,0.f};
        f32x4 a2 = {0.f,0.f,0.f,0.f}, a3 = {0.f,0.f,0.f,0.f};
        float ws = 0.f;
        for (int j = 0; j < m; j += 4) {
            uint2 sw0 = lsw[base + j];              // broadcast b64 reads
            uint2 sw1 = lsw[base + j + 1];
            uint2 sw2 = lsw[base + j + 2];
            uint2 sw3 = lsw[base + j + 3];
            bool o1 = (j + 1) < m, o2 = (j + 2) < m, o3 = (j + 3) < m;
            unsigned s0 = sw0.x;
            unsigned s1 = o1 ? sw1.x : 0u;
            unsigned s2 = o2 ? sw2.x : 0u;
            unsigned s3 = o3 ? sw3.x : 0u;
            float w0 = __uint_as_float(sw0.y);
            float w1 = o1 ? __uint_as_float(sw1.y) : 0.f;
            float w2 = o2 ? __uint_as_float(sw2.y) : 0.f;
            float w3 = o3 ? __uint_as_float(sw3.y) : 0.f;
            unsigned u0 = h4[s0 * 32 + col];
            unsigned u1 = h4[s1 * 32 + col];
            unsigned u2 = h4[s2 * 32 + col];
            unsigned u3 = h4[s3 * 32 + col];
            ws += (w0 + w1) + (w2 + w3);
            a0 += unpk4u(u0) * w0;
            a1 += unpk4u(u1) * w1;
            a2 += unpk4u(u2) * w2;
            a3 += unpk4u(u3) * w3;
        }
        f32x4 acc = (a0 + a1) + (a2 + a3);

        if (valid) {
            const float di = rsqrtf((float)deg + 1.0f);
            const float ci = di * rscale[i];
            unsigned uv = h4[i * 32 + col];
            f32x4 hv = unpk4u(uv);
            const float corr = 128.f * (ws + ci);   // bias corr (incl. self)
            float4 o4;
            o4.x = bb.x + di * (acc[0] + ci * hv[0] - corr);
            o4.y = bb.y + di * (acc[1] + ci * hv[1] - corr);
            o4.z = bb.z + di * (acc[2] + ci * hv[2] - corr);
            o4.w = bb.w + di * (acc[3] + ci * hv[3] - corr);
            ((float4*)out)[i * 32 + col] = o4;
        }
    }
}

// ---------------------------------------------------------------------------
extern "C" void kernel_launch(void* const* d_in, const int* in_sizes, int n_in,
                              void* d_out, int out_size, void* d_ws, size_t ws_size,
                              hipStream_t stream) {
    const float* x  = (const float*)d_in[0];
    const int*   ei = (const int*)d_in[1];
    const float* W  = (const float*)d_in[2];
    const float* b  = (const float*)d_in[3];
    float* out = (float*)d_out;

    // ws layout (4B-unit offsets):
    // h8 [0..3.2M) | rscale 3.3M | combo 3.45M | bcur 4.13M |
    // Wimg 4.14M (34.8KB) | ebuf [4.3M .. 4.3M+782*2432=6.20M)
    signed char* h8 = (signed char*)d_ws;
    float* rscale = (float*)d_ws + 3300000;
    float* combo  = (float*)d_ws + 3450000;
    int*   bcur   = (int*)d_ws + 4130000;
    u16*   Wimg   = (u16*)((int*)d_ws + 4140000);
    unsigned int* ebuf = (unsigned int*)d_ws + 4300000;

    prep_kernel<<<16, 256, 0, stream>>>(W, Wimg, bcur);
    fused1_kernel<<<NCHUNK + GEMM_BLOCKS, 256, 0, stream>>>(x, Wimg, h8, rscale,
                                                            ei, bcur, ebuf);
    comboK_kernel<<<NBUCK, 256, 0, stream>>>(ebuf, bcur, rscale, combo);
    aggB_kernel<<<NBUCK * 2, 256, 0, stream>>>(ebuf, bcur, rscale, combo, h8, b, out);
}